// Round 8
// baseline (49.706 us; speedup 1.0000x reference)
//
#include <hip/hip_runtime.h>
#include <math.h>

#define BATCH 128
#define NPWM 512
#define LEN 1000
#define NPOS 982
#define NEXT 1024     // 2*NPWM (fwd + revcomp interleaved: f_ext = 2*f + strand)
#define KSLOT 80      // kk padded 19->20, slot = kk*4 + c

typedef __bf16 bf16x4 __attribute__((ext_vector_type(4)));
typedef __bf16 bf16x8 __attribute__((ext_vector_type(8)));
typedef float  f32x16 __attribute__((ext_vector_type(16)));

#define MFMA32(a, b, c) __builtin_amdgcn_mfma_f32_32x32x16_bf16(a, b, c, 0, 0, 0)

// ---- prepack W: (512,4,19) fp32 -> (1024,80) bf16 hi/lo, zeros at pad slots ----
__global__ __launch_bounds__(256)
void prepack_w(const float* __restrict__ w, __bf16* __restrict__ whi, __bf16* __restrict__ wlo)
{
    int idx = blockIdx.x * 256 + threadIdx.x;
    if (idx >= NEXT * KSLOT) return;
    int fe = idx / KSLOT;
    int t  = idx - fe * KSLOT;
    int kk = t >> 2;
    int c  = t & 3;
    int f      = fe >> 1;
    int strand = fe & 1;
    float v = 0.0f;
    if (kk < 19)
        v = strand ? w[f*76 + (3-c)*19 + (18-kk)]   // reverse-complement
                   : w[f*76 + c*19 + kk];
    __bf16 h = (__bf16)v;
    whi[idx] = h;
    wlo[idx] = (__bf16)(v - (float)h);
}

// one K-sweep over 32 positions starting at (IT)*32.
// 10 products partitioned round-robin into 3 independent chains (4/3/3 deep):
//   idx(t,hi)=2t, idx(t,lo)=2t+1; chain = idx % 3.
// B reads: paired ds_read_b64 (8B-aligned, conflict-free in [pos][c] layout).
#define KBODY(IT, MASKED)                                               \
  {                                                                     \
    f32x16 c0 = {}, c1 = {}, c2 = {};                                   \
    const int e0 = (IT)*128 + cgh4;                                     \
    bf16x4 b0, b1; bf16x8 bh;                                           \
    b0 = *(const bf16x4*)(H + e0);                                      \
    b1 = *(const bf16x4*)(H + e0 + 4);                                  \
    bh = __builtin_shufflevector(b0, b1, 0,1,2,3,4,5,6,7);              \
    c0 = MFMA32(wah[0], bh, c0);   /* idx 0 */                          \
    c1 = MFMA32(wal[0], bh, c1);   /* idx 1 */                          \
    b0 = *(const bf16x4*)(H + e0 + 16);                                 \
    b1 = *(const bf16x4*)(H + e0 + 20);                                 \
    bh = __builtin_shufflevector(b0, b1, 0,1,2,3,4,5,6,7);              \
    c2 = MFMA32(wah[1], bh, c2);   /* idx 2 */                          \
    c0 = MFMA32(wal[1], bh, c0);   /* idx 3 */                          \
    b0 = *(const bf16x4*)(H + e0 + 32);                                 \
    b1 = *(const bf16x4*)(H + e0 + 36);                                 \
    bh = __builtin_shufflevector(b0, b1, 0,1,2,3,4,5,6,7);              \
    c1 = MFMA32(wah[2], bh, c1);   /* idx 4 */                          \
    c2 = MFMA32(wal[2], bh, c2);   /* idx 5 */                          \
    b0 = *(const bf16x4*)(H + e0 + 48);                                 \
    b1 = *(const bf16x4*)(H + e0 + 52);                                 \
    bh = __builtin_shufflevector(b0, b1, 0,1,2,3,4,5,6,7);              \
    c0 = MFMA32(wah[3], bh, c0);   /* idx 6 */                          \
    c1 = MFMA32(wal[3], bh, c1);   /* idx 7 */                          \
    b0 = *(const bf16x4*)(H + e0 + 64);                                 \
    b1 = *(const bf16x4*)(H + e0 + 68);                                 \
    bh = __builtin_shufflevector(b0, b1, 0,1,2,3,4,5,6,7);              \
    c2 = MFMA32(wah[4], bh, c2);   /* idx 8 */                          \
    c0 = MFMA32(wal[4], bh, c0);   /* idx 9 */                          \
    if (!(MASKED) || col < 22) {                                        \
      _Pragma("unroll")                                                 \
      for (int r = 0; r < 16; ++r)                                      \
        m[r] = fmaxf(m[r], (c0[r] + c1[r]) + c2[r]);                    \
    }                                                                   \
  }

// ---- main: 2-term w-split GEMM, 32x32x16, fg=1, 3 acc chains, fused max ----
// block = 4 waves = 2 filter-tiles x 2 position-halves; grid = (128,16).
__global__ __launch_bounds__(256, 4)
void pwm_mfma(const float* __restrict__ x,
              const __bf16* __restrict__ whi,
              const __bf16* __restrict__ wlo,
              float* __restrict__ out)
{
    __shared__ __align__(16) __bf16 H[4096];   // bf16(x), [pos][c], pos 0..1023 (tail 0)
    __shared__ float red[2][64];

    const int tid   = threadIdx.x;
    const int b     = blockIdx.x;
    const int by    = blockIdx.y;   // 0..15: which 64 f_ext
    const int lane  = tid & 63;
    const int wave  = tid >> 6;
    const int fhalf = wave & 1;     // which 32-filter tile
    const int wp    = wave >> 1;    // position half
    const int col   = lane & 31;
    const int gh    = lane >> 5;

    // stage bf16(x[b]) position-major [pos][c]; 8B LDS writes, tail zeroed
    for (int i = tid; i < 1024; i += 256) {
        bf16x4 hv;
        #pragma unroll
        for (int c = 0; c < 4; ++c) {
            float v = (i < LEN) ? x[(size_t)b*4000 + c*1000 + i] : 0.0f;
            hv[c] = (__bf16)v;
        }
        *(bf16x4*)(H + i*4) = hv;
    }

    // A fragments (W hi/lo) -> regs: lane holds W[f0+col][k = t*16 + gh*8 + j]
    bf16x8 wah[5], wal[5];
    {
        const int f0 = by*64 + fhalf*32;
        #pragma unroll
        for (int t = 0; t < 5; ++t) {
            const size_t o = (size_t)(f0 + col)*KSLOT + t*16 + gh*8;
            wah[t] = *(const bf16x8*)(whi + o);
            wal[t] = *(const bf16x8*)(wlo + o);
        }
    }
    __syncthreads();

    // B element base: slot k = t*16 + gh*8 + j -> x element (pos + t*4 + 2gh)*4 + c
    const int cgh4 = (col + 2*gh)*4;

    f32x16 m;
    #pragma unroll
    for (int r = 0; r < 16; ++r) m[r] = -INFINITY;

    if (wp == 0) {
        for (int it = 0; it < 16; ++it) KBODY(it, false)
    } else {
        for (int it = 16; it < 30; ++it) KBODY(it, false)
        KBODY(30, true)   // pos = 960+col; mask pos >= 982
    }

    // reduce over the 32 position-columns (within each 32-lane half)
    #pragma unroll
    for (int off = 1; off <= 16; off <<= 1)
        #pragma unroll
        for (int r = 0; r < 16; ++r)
            m[r] = fmaxf(m[r], __shfl_xor(m[r], off, 64));

    // D row (f_ext within 32-tile) = (r&3) + 8*(r>>2) + 4*gh
    if (col == 0) {
        #pragma unroll
        for (int r = 0; r < 16; ++r) {
            const int row = (r & 3) + 8*(r >> 2) + 4*gh;
            red[wp][fhalf*32 + row] = m[r];
        }
    }
    __syncthreads();
    if (tid < 32) {   // combine strand pairs (f_ext = 2f, 2f+1) and position halves
        float v0 = fmaxf(red[0][2*tid], red[0][2*tid+1]);
        float v1 = fmaxf(red[1][2*tid], red[1][2*tid+1]);
        out[(size_t)b*NPWM + by*32 + tid] = fmaxf(v0, v1);
    }
}

extern "C" void kernel_launch(void* const* d_in, const int* in_sizes, int n_in,
                              void* d_out, int out_size, void* d_ws, size_t ws_size,
                              hipStream_t stream)
{
    const float* x = (const float*)d_in[0];   // (128, 4, 1000)
    const float* w = (const float*)d_in[1];   // (512, 4, 19)
    float* out = (float*)d_out;               // (128, 512)

    __bf16* whi = (__bf16*)d_ws;              // 1024*80 bf16
    __bf16* wlo = whi + NEXT*KSLOT;

    prepack_w<<<dim3((NEXT*KSLOT + 255)/256), 256, 0, stream>>>(w, whi, wlo);
    pwm_mfma<<<dim3(BATCH, 16), 256, 0, stream>>>(x, whi, wlo, out);
}

// Round 9
// 45.639 us; speedup vs baseline: 1.0891x; 1.0891x over previous
//
#include <hip/hip_runtime.h>
#include <math.h>

#define BATCH 128
#define NPWM 512
#define LEN 1000
#define NPOS 982
#define NEXT 1024     // 2*NPWM (fwd + revcomp interleaved: f_ext = 2*f + strand)
#define KSLOT 80      // kk padded 19->20, slot = kk*4 + c

typedef __bf16 bf16x4 __attribute__((ext_vector_type(4)));
typedef __bf16 bf16x8 __attribute__((ext_vector_type(8)));
typedef float  f32x16 __attribute__((ext_vector_type(16)));

#define MFMA32(a, b, c) __builtin_amdgcn_mfma_f32_32x32x16_bf16(a, b, c, 0, 0, 0)

// ---- prepack W: (512,4,19) fp32 -> (1024,80) bf16 hi/lo, zeros at pad slots ----
__global__ __launch_bounds__(256)
void prepack_w(const float* __restrict__ w, __bf16* __restrict__ whi, __bf16* __restrict__ wlo)
{
    int idx = blockIdx.x * 256 + threadIdx.x;
    if (idx >= NEXT * KSLOT) return;
    int fe = idx / KSLOT;
    int t  = idx - fe * KSLOT;
    int kk = t >> 2;
    int c  = t & 3;
    int f      = fe >> 1;
    int strand = fe & 1;
    float v = 0.0f;
    if (kk < 19)
        v = strand ? w[f*76 + (3-c)*19 + (18-kk)]   // reverse-complement
                   : w[f*76 + c*19 + kk];
    __bf16 h = (__bf16)v;
    whi[idx] = h;
    wlo[idx] = (__bf16)(v - (float)h);
}

// single 10-deep MFMA chain over one 32-position tile (B regs pre-loaded)
#define CHAIN10(BUF, A)                                                 \
    A = MFMA32(wah[0], BUF[0], A); A = MFMA32(wal[0], BUF[0], A);       \
    A = MFMA32(wah[1], BUF[1], A); A = MFMA32(wal[1], BUF[1], A);       \
    A = MFMA32(wah[2], BUF[2], A); A = MFMA32(wal[2], BUF[2], A);       \
    A = MFMA32(wah[3], BUF[3], A); A = MFMA32(wal[3], BUF[3], A);       \
    A = MFMA32(wah[4], BUF[4], A); A = MFMA32(wal[4], BUF[4], A);

// ---- main: 2-term w-split GEMM, 32x32x16, B reg-prefetch ping-pong, 2 batches ----
// block = 4 waves = 2 filter-tiles x 2 position-halves; grid = (64,16) = 4 blocks/CU.
__global__ __launch_bounds__(256, 4)
void pwm_mfma(const float* __restrict__ x,
              const __bf16* __restrict__ whi,
              const __bf16* __restrict__ wlo,
              float* __restrict__ out)
{
    __shared__ __align__(16) __bf16 H[2][4096];  // bf16(x), [batch][pos*4+c], tail 0
    __shared__ float red[2][64];

    const int tid   = threadIdx.x;
    const int b0    = blockIdx.x * 2;  // two batches per block
    const int by    = blockIdx.y;      // 0..15: which 64 f_ext
    const int lane  = tid & 63;
    const int wave  = tid >> 6;
    const int fhalf = wave & 1;        // which 32-filter tile
    const int wp    = wave >> 1;       // position half
    const int col   = lane & 31;
    const int gh    = lane >> 5;

    // stage bf16(x) for both batches, position-major [pos][c]
    for (int i = tid; i < 2048; i += 256) {
        const int bb = i >> 10, p = i & 1023;
        bf16x4 hv;
        #pragma unroll
        for (int c = 0; c < 4; ++c) {
            float v = (p < LEN) ? x[(size_t)(b0 + bb)*4000 + c*1000 + p] : 0.0f;
            hv[c] = (__bf16)v;
        }
        *(bf16x4*)(&H[bb][p*4]) = hv;
    }

    // A fragments (W hi/lo) -> regs: lane holds W[f0+col][k = t*16 + gh*8 + j]
    bf16x8 wah[5], wal[5];
    {
        const int f0 = by*64 + fhalf*32;
        #pragma unroll
        for (int t = 0; t < 5; ++t) {
            const size_t o = (size_t)(f0 + col)*KSLOT + t*16 + gh*8;
            wah[t] = *(const bf16x8*)(whi + o);
            wal[t] = *(const bf16x8*)(wlo + o);
        }
    }
    __syncthreads();

    const int cgh4 = (col + 2*gh)*4;
    const int beg  = wp ? 16 : 0;
    const int n    = wp ? 14 : 16;     // unmasked pipelined iters (even)

    for (int bb = 0; bb < 2; ++bb) {
        const __bf16* Hb = &H[bb][0];

        auto LOADP = [&](int it, int t) -> bf16x8 {
            const int e0 = it*128 + cgh4 + t*16;
            bf16x4 p0 = *(const bf16x4*)(Hb + e0);
            bf16x4 p1 = *(const bf16x4*)(Hb + e0 + 4);
            return __builtin_shufflevector(p0, p1, 0,1,2,3,4,5,6,7);
        };

        f32x16 m;
        #pragma unroll
        for (int r = 0; r < 16; ++r) m[r] = -INFINITY;

        bf16x8 bA[5], bB[5];
        #pragma unroll
        for (int t = 0; t < 5; ++t) bA[t] = LOADP(beg, t);

        for (int ii = 0; ii < n; ii += 2) {
            const int it0 = beg + ii;
            // iter it0: prefetch it0+1 -> bB, compute from bA
            #pragma unroll
            for (int t = 0; t < 5; ++t) bB[t] = LOADP(it0 + 1, t);
            {
                f32x16 a = {};
                CHAIN10(bA, a)
                #pragma unroll
                for (int r = 0; r < 16; ++r) m[r] = fmaxf(m[r], a[r]);
            }
            // iter it0+1: prefetch next (or tail it=30 for wp1) -> bA, compute from bB
            const int itn = (ii + 2 < n) ? it0 + 2 : (wp ? 30 : beg);
            #pragma unroll
            for (int t = 0; t < 5; ++t) bA[t] = LOADP(itn, t);
            {
                f32x16 a = {};
                CHAIN10(bB, a)
                #pragma unroll
                for (int r = 0; r < 16; ++r) m[r] = fmaxf(m[r], a[r]);
            }
        }
        if (wp) {   // masked tail iter it=30 (pos = 960+col; keep pos < 982)
            f32x16 a = {};
            CHAIN10(bA, a)
            if (col < 22) {
                #pragma unroll
                for (int r = 0; r < 16; ++r) m[r] = fmaxf(m[r], a[r]);
            }
        }

        // reduce over the 32 position-columns (within each 32-lane half)
        #pragma unroll
        for (int off = 1; off <= 16; off <<= 1)
            #pragma unroll
            for (int r = 0; r < 16; ++r)
                m[r] = fmaxf(m[r], __shfl_xor(m[r], off, 64));

        // D row (f_ext within 32-tile) = (r&3) + 8*(r>>2) + 4*gh
        if (col == 0) {
            #pragma unroll
            for (int r = 0; r < 16; ++r) {
                const int row = (r & 3) + 8*(r >> 2) + 4*gh;
                red[wp][fhalf*32 + row] = m[r];
            }
        }
        __syncthreads();
        if (tid < 32) {   // combine strand pairs (f_ext = 2f, 2f+1) and position halves
            float v0 = fmaxf(red[0][2*tid], red[0][2*tid+1]);
            float v1 = fmaxf(red[1][2*tid], red[1][2*tid+1]);
            out[(size_t)(b0 + bb)*NPWM + by*32 + tid] = fmaxf(v0, v1);
        }
        __syncthreads();  // protect red before next batch reuses it
    }
}

extern "C" void kernel_launch(void* const* d_in, const int* in_sizes, int n_in,
                              void* d_out, int out_size, void* d_ws, size_t ws_size,
                              hipStream_t stream)
{
    const float* x = (const float*)d_in[0];   // (128, 4, 1000)
    const float* w = (const float*)d_in[1];   // (512, 4, 19)
    float* out = (float*)d_out;               // (128, 512)

    __bf16* whi = (__bf16*)d_ws;              // 1024*80 bf16
    __bf16* wlo = whi + NEXT*KSLOT;

    prepack_w<<<dim3((NEXT*KSLOT + 255)/256), 256, 0, stream>>>(w, whi, wlo);
    pwm_mfma<<<dim3(BATCH/2, 16), 256, 0, stream>>>(x, whi, wlo, out);
}